// Round 12
// baseline (624.036 us; speedup 1.0000x reference)
//
#include <hip/hip_runtime.h>
#include <hip/hip_bf16.h>

#define BB 2
#define SS 2048
#define HH 16
#define LN_EPS 1e-5f
#define LOG2E 1.44269504088896f

typedef __attribute__((ext_vector_type(8))) short short8;
typedef __attribute__((ext_vector_type(4))) float floatx4;

#define EXP2F(x) __builtin_amdgcn_exp2f(x)
#define GLOAD16(g, l) __builtin_amdgcn_global_load_lds( \
    (const __attribute__((address_space(1))) void*)(g), \
    (__attribute__((address_space(3))) void*)(l), 16, 0, 0)

__device__ __forceinline__ ushort f2b(float f) {
    union { float f; unsigned u; } x; x.f = f;
    unsigned u = x.u;
    return (ushort)((u + 0x7FFFu + ((u >> 16) & 1u)) >> 16);
}
__device__ __forceinline__ float b2f(ushort u) {
    union { unsigned u; float f; } x; x.u = ((unsigned)u) << 16;
    return x.f;
}

// ---------------- fused prep: fp32->bf16 convert (z<3) + W transpose (z>=3) ----------------
__global__ __launch_bounds__(256) void prep(
    const float* __restrict__ Q, const float* __restrict__ K, const float* __restrict__ V,
    const float* __restrict__ W0, const float* __restrict__ W1,
    const float* __restrict__ W2, const float* __restrict__ W3,
    ushort* __restrict__ Xq, ushort* __restrict__ Xk, ushort* __restrict__ Xv,
    ushort* __restrict__ T0, ushort* __restrict__ T1,
    ushort* __restrict__ T2, ushort* __restrict__ T3)
{
    __shared__ float ts[32][33];
    const int z = blockIdx.z;
    if (z < 3) {
        const float* X = z == 0 ? Q : z == 1 ? K : V;
        ushort* Y = z == 0 ? Xq : z == 1 ? Xk : Xv;
        const size_t i = ((size_t)blockIdx.x * 256 + threadIdx.x) * 8;
        float4 a = *(const float4*)&X[i];
        float4 b = *(const float4*)&X[i + 4];
        short8 o;
        o[0] = (short)f2b(a.x); o[1] = (short)f2b(a.y); o[2] = (short)f2b(a.z); o[3] = (short)f2b(a.w);
        o[4] = (short)f2b(b.x); o[5] = (short)f2b(b.y); o[6] = (short)f2b(b.z); o[7] = (short)f2b(b.w);
        *(short8*)&Y[i] = o;
    } else {
        if (blockIdx.x >= 1024) return;
        const int zz = z - 3;
        const float* W = zz == 0 ? W0 : zz == 1 ? W1 : zz == 2 ? W2 : W3;
        ushort* T = zz == 0 ? T0 : zz == 1 ? T1 : zz == 2 ? T2 : T3;
        const float scale = (zz == 0) ? 0.125f : 1.0f;  // fold 1/sqrt(DK) into Wq
        const int k0 = (blockIdx.x >> 5) * 32, n0 = (blockIdx.x & 31) * 32;
        const int r = threadIdx.x >> 3, c4 = (threadIdx.x & 7) * 4;
        float4 v = *(const float4*)&W[(size_t)(k0 + r) * 1024 + n0 + c4];
        ts[r][c4 + 0] = v.x; ts[r][c4 + 1] = v.y; ts[r][c4 + 2] = v.z; ts[r][c4 + 3] = v.w;
        __syncthreads();
        ushort4 o;
        o.x = f2b(ts[c4 + 0][r] * scale); o.y = f2b(ts[c4 + 1][r] * scale);
        o.z = f2b(ts[c4 + 2][r] * scale); o.w = f2b(ts[c4 + 3][r] * scale);
        *(ushort4*)&T[(size_t)(n0 + r) * 1024 + k0 + c4] = o;
    }
}

// ---------------- MFMA GEMM: 128x(NB*32) tile, BK=32, 2-phase dbuf global_load_lds ----------------
// Carries a side-duty: streams `nfill` 64x64 zero tiles of the attn matrix (flat index f_lo..),
// one tile per K-iteration, using otherwise-idle store bandwidth.
// Flat tile space: bh in [0,32), per bh 756 tiles: per qblk q, L=max(0,q-4) left tiles
// (cols [0,jstart)) then R=max(0,27-q) right tiles (cols [jend,2048)); cnt(q) in [23,27], never 0.
template<int NB>  // NB=4: 128x128 (acc 4x4); NB=2: 128x64 (acc 4x2)
__device__ __forceinline__ void gemm_body(
    const ushort* __restrict__ Ab, const ushort* __restrict__ Bt,
    const float* __restrict__ bias, float bscale,
    float* Cf, ushort* Cb, int m0, int n0,
    float* __restrict__ attnf, int f_lo, int f_hi)
{
    __shared__ ushort As[2][128 * 32];
    __shared__ ushort Bs[2][NB * 32 * 32];
    const int t = threadIdx.x;
    const int l = t & 63;
    const int w = t >> 6;
    const int wm = w >> 1, wn = w & 1;

    floatx4 acc[4][NB] = {};

    const int i0c = w * 64 + l;
    const int r0 = i0c >> 2, c0 = i0c & 3;
    const int i1c = 256 + i0c;
    const int r1 = i1c >> 2, c1 = i1c & 3;

    const ushort* gA0 = &Ab[(size_t)(m0 + r0) * 1024 + c0 * 8];
    const ushort* gA1 = &Ab[(size_t)(m0 + r1) * 1024 + c1 * 8];
    const ushort* gB0 = &Bt[(size_t)(n0 + r0) * 1024 + c0 * 8];
    const ushort* gB1 = &Bt[(size_t)(n0 + ((NB == 4) ? r1 : r0)) * 1024 + ((NB == 4) ? c1 : c0) * 8];

    const int d0 = (w * 64) * 16;
    const int d1 = (256 + w * 64) * 16;

    // ---- zero-fill iterator state ----
    int fleft = f_hi - f_lo;
    int fbh = 0, fq = 0, frr = 0;
    if (fleft > 0) {
        fbh = f_lo / 756;
        int r = f_lo - fbh * 756;
        while (true) {
            int cnt = (fq > 4 ? fq - 4 : 0) + (fq < 27 ? 27 - fq : 0);
            if (r < cnt) break;
            r -= cnt; ++fq;
        }
        frr = r;
    }
    const int ftrow = t >> 2, ftc = (t & 3) * 16;
    const floatx4 fz = {0.f, 0.f, 0.f, 0.f};

    // prologue: stage k0=0 into buf 0
    GLOAD16(gA0, (char*)As[0] + d0);
    GLOAD16(gA1, (char*)As[0] + d1);
    GLOAD16(gB0, (char*)Bs[0] + d0);
    if (NB == 4) GLOAD16(gB1, (char*)Bs[0] + d1);
    __syncthreads();

    int cur = 0;
    for (int k0 = 0; k0 < 1024; k0 += 32) {
        if (k0 + 32 < 1024) {  // issue next-tile stage before compute
            GLOAD16(gA0 + k0 + 32, (char*)As[cur ^ 1] + d0);
            GLOAD16(gA1 + k0 + 32, (char*)As[cur ^ 1] + d1);
            GLOAD16(gB0 + k0 + 32, (char*)Bs[cur ^ 1] + d0);
            if (NB == 4) GLOAD16(gB1 + k0 + 32, (char*)Bs[cur ^ 1] + d1);
        }
        // ---- emit one zero tile (fire-and-forget NT stores; ack'd by L2 under compute) ----
        if (fleft > 0) {
            int L = fq > 4 ? fq - 4 : 0;
            int col = (frr < L) ? frr * 64 : (fq * 64 + 320 + (frr - L) * 64);
            float* fp = attnf + (size_t)fbh * ((size_t)SS * SS)
                      + (size_t)(fq * 64 + ftrow) * SS + col + ftc;
            __builtin_nontemporal_store(fz, (floatx4*)fp);
            __builtin_nontemporal_store(fz, (floatx4*)(fp + 4));
            __builtin_nontemporal_store(fz, (floatx4*)(fp + 8));
            __builtin_nontemporal_store(fz, (floatx4*)(fp + 12));
            --fleft; ++frr;
            int cnt = L + (fq < 27 ? 27 - fq : 0);
            if (frr >= cnt) { frr = 0; ++fq; if (fq == 32) { fq = 0; ++fbh; } }
        }
        short8 af[4], bf[NB];
#pragma unroll
        for (int m = 0; m < 4; ++m)
            af[m] = *(const short8*)&As[cur][(wm * 64 + m * 16 + (l & 15)) * 32 + (l >> 4) * 8];
#pragma unroll
        for (int n = 0; n < NB; ++n)
            bf[n] = *(const short8*)&Bs[cur][(wn * (NB * 16) + n * 16 + (l & 15)) * 32 + (l >> 4) * 8];
#pragma unroll
        for (int m = 0; m < 4; ++m)
#pragma unroll
            for (int n = 0; n < NB; ++n)
                acc[m][n] = __builtin_amdgcn_mfma_f32_16x16x32_bf16(af[m], bf[n], acc[m][n], 0, 0, 0);
        __syncthreads();   // drains next-tile stage (latency hidden under MFMAs)
        cur ^= 1;
    }

    const int cr = (l >> 4) * 4;
    const int cc = l & 15;
#pragma unroll
    for (int n = 0; n < NB; ++n) {
        int col = n0 + wn * (NB * 16) + n * 16 + cc;
        float bv = bias[col] * bscale;
#pragma unroll
        for (int m = 0; m < 4; ++m) {
            int row = m0 + wm * 64 + m * 16 + cr;
#pragma unroll
            for (int j = 0; j < 4; ++j) {
                float v = acc[m][n][j] + bv;
                if (Cf) Cf[(size_t)(row + j) * 1024 + col] = v;
                else    Cb[(size_t)(row + j) * 1024 + col] = f2b(v);
            }
        }
    }
}

__global__ __launch_bounds__(256) void gemm_qkv(
    const ushort* __restrict__ Xq, const ushort* __restrict__ Xk, const ushort* __restrict__ Xv,
    const ushort* __restrict__ Wqt, const ushort* __restrict__ Wkt, const ushort* __restrict__ Wvt,
    const float* __restrict__ bq, const float* __restrict__ bk, const float* __restrict__ bv,
    ushort* __restrict__ qp, ushort* __restrict__ kp, ushort* __restrict__ vp,
    float* __restrict__ attnf)
{
    const int z = blockIdx.z;
    const ushort* A = z == 0 ? Xq : z == 1 ? Xk : Xv;
    const ushort* Bt = z == 0 ? Wqt : z == 1 ? Wkt : Wvt;
    const float* bias = z == 0 ? bq : z == 1 ? bk : bv;
    ushort* C = z == 0 ? qp : z == 1 ? kp : vp;
    float bscale = (z == 0) ? 0.125f : 1.0f;
    // 256 blocks/slice: each XCD owns 4 contiguous m-panels x all 8 n-tiles (128x128)
    int bid = blockIdx.x + (blockIdx.y << 3);   // 0..255
    int xcd = bid & 7, idx = bid >> 3;
    int m0 = (xcd * 4 + (idx & 3)) * 128;
    int n0 = (idx >> 2) * 128;
    // fill duty: 768 blocks x 21 tiles = tiles [0, 16128)
    int k = bid + z * 256;
    gemm_body<4>(A, Bt, bias, bscale, nullptr, C, m0, n0, attnf, k * 21, k * 21 + 21);
}

__global__ __launch_bounds__(256) void gemm_obf(
    const ushort* __restrict__ ctxb, const ushort* __restrict__ Wot,
    const float* __restrict__ bo, float* __restrict__ op,
    float* __restrict__ attnf)
{
    // 512 blocks (2/CU): 128x64 tiles
    int bid = blockIdx.x + (blockIdx.y << 3);   // grid (8,64) -> 0..511
    int xcd = bid & 7, idx = bid >> 3;          // idx 0..63
    int m0 = (xcd * 4 + (idx & 3)) * 128;
    int n0 = (idx >> 2) * 64;
    // fill duty: tiles [16128, 24192), 16 per block (blocks >= 504 get none)
    int lo = 16128 + bid * 16;
    int hi = lo + 16; if (hi > 24192) hi = 24192; if (lo > 24192) lo = 24192;
    gemm_body<2>(ctxb, Wot, bo, 1.0f, op, nullptr, m0, n0, attnf, lo, hi);
}

// ---------------- MFMA banded attention: 64 q-rows/block, 4 waves x 16 rows ----------------
// Band-only writes (zeros are streamed by the GEMM kernels); K direct from global (L2-resident);
// V double-buffered in LDS (transpose needed).
__global__ __launch_bounds__(256, 4) void attn_mfma(
    const ushort* __restrict__ qb, const ushort* __restrict__ kb, const ushort* __restrict__ vb,
    float* __restrict__ attn, ushort* __restrict__ ctxb)
{
    __shared__ alignas(16) ushort Vt[2][64 * 72];
    __shared__ alignas(16) ushort Pl[4][16 * 72];

    const int qblk = blockIdx.x, h = blockIdx.y, b = blockIdx.z;
    const int i0 = qblk * 64;
    const int t = threadIdx.x;
    const int w = t >> 6, l = t & 63;
    const int g = l >> 4, c = l & 15;
    const int ibase = i0 + w * 16;

    const int jstart = max(0, i0 - 256);            // 64-aligned
    const int jend = min(SS, i0 + 64 + 256);        // 64-aligned

    // Q A-fragments (rows ibase..ibase+15, pre-scaled via Wq)
    const size_t qoff = (size_t)(b * SS + ibase + c) * 1024 + h * 64 + g * 8;
    short8 aq0 = *(const short8*)&qb[qoff];
    short8 aq1 = *(const short8*)&qb[qoff + 32];

    const int vj0 = (t & 31) * 2, vd0 = (t >> 5) * 8;
    const ushort* Kbh = &kb[(size_t)(b * SS) * 1024 + h * 64];

    float m[4] = {-3e38f, -3e38f, -3e38f, -3e38f};
    float ll[4] = {0.f, 0.f, 0.f, 0.f};

    // ---- pass 1: running row max + sum (exp2 domain); K direct from global, no barriers ----
    for (int jt = jstart; jt < jend; jt += 64) {
        const ushort* kt = Kbh + (size_t)jt * 1024;
        floatx4 s[4] = {};
#pragma unroll
        for (int u = 0; u < 4; ++u) {
            short8 b0 = *(const short8*)&kt[(size_t)(u * 16 + c) * 1024 + g * 8];
            short8 b1 = *(const short8*)&kt[(size_t)(u * 16 + c) * 1024 + 32 + g * 8];
            s[u] = __builtin_amdgcn_mfma_f32_16x16x32_bf16(aq0, b0, s[u], 0, 0, 0);
            s[u] = __builtin_amdgcn_mfma_f32_16x16x32_bf16(aq1, b1, s[u], 0, 0, 0);
        }
        const bool full = (jt >= ibase - 240) && (jt <= ibase + 192);
#pragma unroll
        for (int r = 0; r < 4; ++r) {
            float v0 = s[0][r] * LOG2E, v1 = s[1][r] * LOG2E,
                  v2 = s[2][r] * LOG2E, v3 = s[3][r] * LOG2E;
            if (!full) {
                const int i = ibase + g * 4 + r;
                const int j0 = jt + c;
                if ((unsigned)(i - j0 + 255) >= 511u)        v0 = -3e38f;
                if ((unsigned)(i - (j0 + 16) + 255) >= 511u) v1 = -3e38f;
                if ((unsigned)(i - (j0 + 32) + 255) >= 511u) v2 = -3e38f;
                if ((unsigned)(i - (j0 + 48) + 255) >= 511u) v3 = -3e38f;
            }
            float tmax = fmaxf(fmaxf(v0, v1), fmaxf(v2, v3));
            float mn = fmaxf(m[r], tmax);
            float sc_ = EXP2F(m[r] - mn);
            float add = EXP2F(v0 - mn) + EXP2F(v1 - mn)
                      + EXP2F(v2 - mn) + EXP2F(v3 - mn);
            ll[r] = ll[r] * sc_ + add;
            m[r] = mn;
        }
    }

    // ---- finalize softmax stats across the 16 j-lanes of each row ----
    float M[4], invL[4];
#pragma unroll
    for (int r = 0; r < 4; ++r) {
        float mm = m[r];
        mm = fmaxf(mm, __shfl_xor(mm, 1));
        mm = fmaxf(mm, __shfl_xor(mm, 2));
        mm = fmaxf(mm, __shfl_xor(mm, 4));
        mm = fmaxf(mm, __shfl_xor(mm, 8));
        float la = ll[r] * EXP2F(m[r] - mm);
        la += __shfl_xor(la, 1);
        la += __shfl_xor(la, 2);
        la += __shfl_xor(la, 4);
        la += __shfl_xor(la, 8);
        M[r] = mm;
        invL[r] = 1.0f / la;
    }

    // ---- pass 2 prologue: stage V tile jstart into Vt[0] ----
    {
        const ushort* vr = &vb[(size_t)(b * SS + jstart + vj0) * 1024 + h * 64 + vd0];
        short8 v0 = *(const short8*)vr;
        short8 v1 = *(const short8*)(vr + 1024);
#pragma unroll
        for (int e = 0; e < 8; ++e) {
            ushort2 pr; pr.x = (ushort)v0[e]; pr.y = (ushort)v1[e];
            *(ushort2*)&Vt[0][(vd0 + e) * 72 + vj0] = pr;
        }
    }
    __syncthreads();

    // ---- pass 2: probs -> attn + PV; one barrier per tile ----
    floatx4 ctx[4] = {};
    int cur = 0;
    for (int jt = jstart; jt < jend; jt += 64) {
        const bool have = (jt + 64 < jend);
        short8 nv0, nv1;
        if (have) {  // T14: issue next V loads early
            const ushort* vr = &vb[(size_t)(b * SS + jt + 64 + vj0) * 1024 + h * 64 + vd0];
            nv0 = *(const short8*)vr;
            nv1 = *(const short8*)(vr + 1024);
        }
        // QK^T from global K
        const ushort* kt = Kbh + (size_t)jt * 1024;
        floatx4 s[4] = {};
#pragma unroll
        for (int u = 0; u < 4; ++u) {
            short8 b0 = *(const short8*)&kt[(size_t)(u * 16 + c) * 1024 + g * 8];
            short8 b1 = *(const short8*)&kt[(size_t)(u * 16 + c) * 1024 + 32 + g * 8];
            s[u] = __builtin_amdgcn_mfma_f32_16x16x32_bf16(aq0, b0, s[u], 0, 0, 0);
            s[u] = __builtin_amdgcn_mfma_f32_16x16x32_bf16(aq1, b1, s[u], 0, 0, 0);
        }
        const bool full = (jt >= ibase - 240) && (jt <= ibase + 192);
#pragma unroll
        for (int u = 0; u < 4; ++u) {
#pragma unroll
            for (int r = 0; r < 4; ++r) {
                float v = s[u][r] * LOG2E;
                if (!full) {
                    const int i = ibase + g * 4 + r;
                    const int j = jt + u * 16 + c;
                    if ((unsigned)(i - j + 255) >= 511u) v = -3e38f;
                }
                float p = EXP2F(v - M[r]) * invL[r];
                Pl[w][(g * 4 + r) * 72 + u * 16 + c] = f2b(p);
            }
        }
        // write attn band tile (256B contiguous per row-quarter), nontemporal
#pragma unroll
        for (int it = 0; it < 4; ++it) {
            const int row = it * 4 + g;
            ushort4 pw = *(const ushort4*)&Pl[w][row * 72 + c * 4];
            floatx4 o;
            o[0] = b2f(pw.x); o[1] = b2f(pw.y); o[2] = b2f(pw.z); o[3] = b2f(pw.w);
            __builtin_nontemporal_store(o,
                (floatx4*)&attn[(size_t)(b * HH + h) * SS * SS + (size_t)(ibase + row) * SS + jt + c * 4]);
        }
        // PV: ctx += P @ V  (Vt[cur] staged last iteration)
#pragma unroll
        for (int jc = 0; jc < 2; ++jc) {
            short8 pa = *(const short8*)&Pl[w][c * 72 + jc * 32 + g * 8];
#pragma unroll
            for (int ds = 0; ds < 4; ++ds) {
                short8 bv_ = *(const short8*)&Vt[cur][(ds * 16 + c) * 72 + jc * 32 + g * 8];
                ctx[ds] = __builtin_amdgcn_mfma_f32_16x16x32_bf16(pa, bv_, ctx[ds], 0, 0, 0);
            }
        }
        // T14 write-late: commit next V tile to LDS
        if (have) {
#pragma unroll
            for (int e = 0; e < 8; ++e) {
                ushort2 pr; pr.x = (ushort)nv0[e]; pr.y = (ushort)nv1[e];
                *(ushort2*)&Vt[cur ^ 1][(vd0 + e) * 72 + vj0] = pr;
            }
        }
        __syncthreads();
        cur ^= 1;
    }

    // ---- ctx out (bf16) ----
#pragma unroll
    for (int ds = 0; ds < 4; ++ds)
#pragma unroll
        for (int r = 0; r < 4; ++r)
            ctxb[(size_t)(b * SS + ibase + g * 4 + r) * 1024 + h * 64 + ds * 16 + c] = f2b(ctx[ds][r]);
}

// ---------------- residual + LayerNorm ----------------
__global__ __launch_bounds__(256) void ln_kernel(
    const float* __restrict__ op, const float* __restrict__ Qin,
    const float* __restrict__ gamma, const float* __restrict__ beta,
    float* __restrict__ y)
{
    const int row = blockIdx.x;
    const int t = threadIdx.x;
    __shared__ float rs[4], rss[4];

    float4 o4 = *(const float4*)&op[(size_t)row * 1024 + t * 4];
    float4 q4 = *(const float4*)&Qin[(size_t)row * 1024 + t * 4];
    float x0 = o4.x + q4.x, x1 = o4.y + q4.y, x2 = o4.z + q4.z, x3 = o4.w + q4.w;
    float s = x0 + x1 + x2 + x3;
    float ss = x0 * x0 + x1 * x1 + x2 * x2 + x3 * x3;
#pragma unroll
    for (int off = 1; off < 64; off <<= 1) {
        s  += __shfl_xor(s, off, 64);
        ss += __shfl_xor(ss, off, 64);
    }
    int wid = t >> 6;
    if ((t & 63) == 0) { rs[wid] = s; rss[wid] = ss; }
    __syncthreads();
    s  = rs[0] + rs[1] + rs[2] + rs[3];
    ss = rss[0] + rss[1] + rss[2] + rss[3];
    float mu = s * (1.0f / 1024.0f);
    float var = ss * (1.0f / 1024.0f) - mu * mu;
    float rstd = rsqrtf(var + LN_EPS);
    float4 g4 = *(const float4*)&gamma[t * 4];
    float4 b4 = *(const float4*)&beta[t * 4];
    float4 o;
    o.x = (x0 - mu) * rstd * g4.x + b4.x;
    o.y = (x1 - mu) * rstd * g4.y + b4.y;
    o.z = (x2 - mu) * rstd * g4.z + b4.z;
    o.w = (x3 - mu) * rstd * g4.w + b4.w;
    *(float4*)&y[(size_t)row * 1024 + t * 4] = o;
}

extern "C" void kernel_launch(void* const* d_in, const int* in_sizes, int n_in,
                              void* d_out, int out_size, void* d_ws, size_t ws_size,
                              hipStream_t stream) {
    (void)in_sizes; (void)n_in; (void)out_size; (void)ws_size;
    const float* Q  = (const float*)d_in[0];
    const float* K  = (const float*)d_in[1];
    const float* V  = (const float*)d_in[2];
    const float* Wq = (const float*)d_in[3];
    const float* bq = (const float*)d_in[4];
    const float* Wk = (const float*)d_in[5];
    const float* bk = (const float*)d_in[6];
    const float* Wv = (const float*)d_in[7];
    const float* bv = (const float*)d_in[8];
    const float* Wo = (const float*)d_in[9];
    const float* bo = (const float*)d_in[10];
    const float* gamma = (const float*)d_in[11];
    const float* beta  = (const float*)d_in[12];

    float* y = (float*)d_out;
    float* attn = y + (size_t)BB * SS * 1024;

    // workspace layout (bytes):
    //  [0,16M):  op (fp32)            -- aliased early by Xq (0-8M) + Xk (8-16M)
    //  [16M,24M): ctxb (bf16)         -- aliased early by Xv
    //  [24M,48M): qbp/kbp/vbp (bf16)
    //  [48M,56M): Wqt/Wkt/Wvt/Wot (bf16)
    char* base = (char*)d_ws;
    float*  op   = (float*)base;
    ushort* Xq   = (ushort*)base;                         // dead after gemm_qkv
    ushort* Xk   = (ushort*)(base + (size_t)8 * 1048576);
    ushort* Xv   = (ushort*)(base + (size_t)16 * 1048576);
    ushort* ctxb = (ushort*)(base + (size_t)16 * 1048576);
    ushort* qbp  = (ushort*)(base + (size_t)24 * 1048576);
    ushort* kbp  = (ushort*)(base + (size_t)32 * 1048576);
    ushort* vbp  = (ushort*)(base + (size_t)40 * 1048576);
    ushort* Wqt  = (ushort*)(base + (size_t)48 * 1048576);
    ushort* Wkt  = (ushort*)(base + (size_t)50 * 1048576);
    ushort* Wvt  = (ushort*)(base + (size_t)52 * 1048576);
    ushort* Wot  = (ushort*)(base + (size_t)54 * 1048576);

    prep<<<dim3(2048, 1, 7), 256, 0, stream>>>(Q, K, V, Wq, Wk, Wv, Wo,
                                               Xq, Xk, Xv, Wqt, Wkt, Wvt, Wot);
    gemm_qkv<<<dim3(8, 32, 3), 256, 0, stream>>>(Xq, Xk, Xv, Wqt, Wkt, Wvt, bq, bk, bv,
                                                 qbp, kbp, vbp, attn);
    attn_mfma<<<dim3(SS / 64, HH, BB), 256, 0, stream>>>(qbp, kbp, vbp, attn, ctxb);
    gemm_obf<<<dim3(8, 64), 256, 0, stream>>>(ctxb, Wot, bo, op, attn);
    ln_kernel<<<4096, 256, 0, stream>>>(op, Q, gamma, beta, y);
}

// Round 13
// 225.811 us; speedup vs baseline: 2.7635x; 2.7635x over previous
//
#include <hip/hip_runtime.h>
#include <hip/hip_bf16.h>

#define BB 2
#define SS 2048
#define HH 16
#define LN_EPS 1e-5f
#define LOG2E 1.44269504088896f

typedef __attribute__((ext_vector_type(8))) short short8;
typedef __attribute__((ext_vector_type(4))) float floatx4;

#define EXP2F(x) __builtin_amdgcn_exp2f(x)
#define GLOAD16(g, l) __builtin_amdgcn_global_load_lds( \
    (const __attribute__((address_space(1))) void*)(g), \
    (__attribute__((address_space(3))) void*)(l), 16, 0, 0)

__device__ __forceinline__ ushort f2b(float f) {
    union { float f; unsigned u; } x; x.f = f;
    unsigned u = x.u;
    return (ushort)((u + 0x7FFFu + ((u >> 16) & 1u)) >> 16);
}
__device__ __forceinline__ float b2f(ushort u) {
    union { unsigned u; float f; } x; x.u = ((unsigned)u) << 16;
    return x.f;
}

// ---------------- fused prep: fp32->bf16 convert (z<3) + W transpose (z>=3) ----------------
__global__ __launch_bounds__(256) void prep(
    const float* __restrict__ Q, const float* __restrict__ K, const float* __restrict__ V,
    const float* __restrict__ W0, const float* __restrict__ W1,
    const float* __restrict__ W2, const float* __restrict__ W3,
    ushort* __restrict__ Xq, ushort* __restrict__ Xk, ushort* __restrict__ Xv,
    ushort* __restrict__ T0, ushort* __restrict__ T1,
    ushort* __restrict__ T2, ushort* __restrict__ T3)
{
    __shared__ float ts[32][33];
    const int z = blockIdx.z;
    if (z < 3) {
        const float* X = z == 0 ? Q : z == 1 ? K : V;
        ushort* Y = z == 0 ? Xq : z == 1 ? Xk : Xv;
        const size_t i = ((size_t)blockIdx.x * 256 + threadIdx.x) * 8;
        float4 a = *(const float4*)&X[i];
        float4 b = *(const float4*)&X[i + 4];
        short8 o;
        o[0] = (short)f2b(a.x); o[1] = (short)f2b(a.y); o[2] = (short)f2b(a.z); o[3] = (short)f2b(a.w);
        o[4] = (short)f2b(b.x); o[5] = (short)f2b(b.y); o[6] = (short)f2b(b.z); o[7] = (short)f2b(b.w);
        *(short8*)&Y[i] = o;
    } else {
        if (blockIdx.x >= 1024) return;
        const int zz = z - 3;
        const float* W = zz == 0 ? W0 : zz == 1 ? W1 : zz == 2 ? W2 : W3;
        ushort* T = zz == 0 ? T0 : zz == 1 ? T1 : zz == 2 ? T2 : T3;
        const float scale = (zz == 0) ? 0.125f : 1.0f;  // fold 1/sqrt(DK) into Wq
        const int k0 = (blockIdx.x >> 5) * 32, n0 = (blockIdx.x & 31) * 32;
        const int r = threadIdx.x >> 3, c4 = (threadIdx.x & 7) * 4;
        float4 v = *(const float4*)&W[(size_t)(k0 + r) * 1024 + n0 + c4];
        ts[r][c4 + 0] = v.x; ts[r][c4 + 1] = v.y; ts[r][c4 + 2] = v.z; ts[r][c4 + 3] = v.w;
        __syncthreads();
        ushort4 o;
        o.x = f2b(ts[c4 + 0][r] * scale); o.y = f2b(ts[c4 + 1][r] * scale);
        o.z = f2b(ts[c4 + 2][r] * scale); o.w = f2b(ts[c4 + 3][r] * scale);
        *(ushort4*)&T[(size_t)(n0 + r) * 1024 + k0 + c4] = o;
    }
}

// ---------------- MFMA GEMM: 128x(NB*32) tile, BK=32, 2-phase dbuf global_load_lds ----------------
template<int NB>  // NB=4: 128x128 (acc 4x4); NB=2: 128x64 (acc 4x2)
__device__ __forceinline__ void gemm_body(
    const ushort* __restrict__ Ab, const ushort* __restrict__ Bt,
    const float* __restrict__ bias, float bscale,
    float* Cf, ushort* Cb, int m0, int n0)
{
    __shared__ ushort As[2][128 * 32];
    __shared__ ushort Bs[2][NB * 32 * 32];
    const int t = threadIdx.x;
    const int l = t & 63;
    const int w = t >> 6;
    const int wm = w >> 1, wn = w & 1;

    floatx4 acc[4][NB] = {};

    const int i0c = w * 64 + l;
    const int r0 = i0c >> 2, c0 = i0c & 3;
    const int i1c = 256 + i0c;
    const int r1 = i1c >> 2, c1 = i1c & 3;

    const ushort* gA0 = &Ab[(size_t)(m0 + r0) * 1024 + c0 * 8];
    const ushort* gA1 = &Ab[(size_t)(m0 + r1) * 1024 + c1 * 8];
    const ushort* gB0 = &Bt[(size_t)(n0 + r0) * 1024 + c0 * 8];
    const ushort* gB1 = &Bt[(size_t)(n0 + ((NB == 4) ? r1 : r0)) * 1024 + ((NB == 4) ? c1 : c0) * 8];

    const int d0 = (w * 64) * 16;
    const int d1 = (256 + w * 64) * 16;

    // prologue: stage k0=0 into buf 0
    GLOAD16(gA0, (char*)As[0] + d0);
    GLOAD16(gA1, (char*)As[0] + d1);
    GLOAD16(gB0, (char*)Bs[0] + d0);
    if (NB == 4) GLOAD16(gB1, (char*)Bs[0] + d1);
    __syncthreads();

    int cur = 0;
    for (int k0 = 0; k0 < 1024; k0 += 32) {
        if (k0 + 32 < 1024) {  // issue next-tile stage before compute
            GLOAD16(gA0 + k0 + 32, (char*)As[cur ^ 1] + d0);
            GLOAD16(gA1 + k0 + 32, (char*)As[cur ^ 1] + d1);
            GLOAD16(gB0 + k0 + 32, (char*)Bs[cur ^ 1] + d0);
            if (NB == 4) GLOAD16(gB1 + k0 + 32, (char*)Bs[cur ^ 1] + d1);
        }
        short8 af[4], bf[NB];
#pragma unroll
        for (int m = 0; m < 4; ++m)
            af[m] = *(const short8*)&As[cur][(wm * 64 + m * 16 + (l & 15)) * 32 + (l >> 4) * 8];
#pragma unroll
        for (int n = 0; n < NB; ++n)
            bf[n] = *(const short8*)&Bs[cur][(wn * (NB * 16) + n * 16 + (l & 15)) * 32 + (l >> 4) * 8];
#pragma unroll
        for (int m = 0; m < 4; ++m)
#pragma unroll
            for (int n = 0; n < NB; ++n)
                acc[m][n] = __builtin_amdgcn_mfma_f32_16x16x32_bf16(af[m], bf[n], acc[m][n], 0, 0, 0);
        __syncthreads();   // drains next-tile stage (latency hidden under MFMAs)
        cur ^= 1;
    }

    const int cr = (l >> 4) * 4;
    const int cc = l & 15;
#pragma unroll
    for (int n = 0; n < NB; ++n) {
        int col = n0 + wn * (NB * 16) + n * 16 + cc;
        float bv = bias[col] * bscale;
#pragma unroll
        for (int m = 0; m < 4; ++m) {
            int row = m0 + wm * 64 + m * 16 + cr;
#pragma unroll
            for (int j = 0; j < 4; ++j) {
                float v = acc[m][n][j] + bv;
                if (Cf) Cf[(size_t)(row + j) * 1024 + col] = v;
                else    Cb[(size_t)(row + j) * 1024 + col] = f2b(v);
            }
        }
    }
}

__global__ __launch_bounds__(256) void gemm_qkv(
    const ushort* __restrict__ Xq, const ushort* __restrict__ Xk, const ushort* __restrict__ Xv,
    const ushort* __restrict__ Wqt, const ushort* __restrict__ Wkt, const ushort* __restrict__ Wvt,
    const float* __restrict__ bq, const float* __restrict__ bk, const float* __restrict__ bv,
    ushort* __restrict__ qp, ushort* __restrict__ kp, ushort* __restrict__ vp)
{
    const int z = blockIdx.z;
    const ushort* A = z == 0 ? Xq : z == 1 ? Xk : Xv;
    const ushort* Bt = z == 0 ? Wqt : z == 1 ? Wkt : Wvt;
    const float* bias = z == 0 ? bq : z == 1 ? bk : bv;
    ushort* C = z == 0 ? qp : z == 1 ? kp : vp;
    float bscale = (z == 0) ? 0.125f : 1.0f;
    // 256 blocks: each XCD owns 4 contiguous m-panels x all 8 n-tiles
    int bid = blockIdx.x + (blockIdx.y << 3);
    int xcd = bid & 7, idx = bid >> 3;
    int m0 = (xcd * 4 + (idx & 3)) * 128;
    int n0 = (idx >> 2) * 128;
    gemm_body<4>(A, Bt, bias, bscale, nullptr, C, m0, n0);
}

__global__ __launch_bounds__(256) void gemm_obf(
    const ushort* __restrict__ ctxb, const ushort* __restrict__ Wot,
    const float* __restrict__ bo, float* __restrict__ op)
{
    // 512 blocks (2/CU): 128x64 tiles
    int bid = blockIdx.x + (blockIdx.y << 3);   // grid (8,64)
    int xcd = bid & 7, idx = bid >> 3;          // idx 0..63
    int m0 = (xcd * 4 + (idx & 3)) * 128;
    int n0 = (idx >> 2) * 64;
    gemm_body<2>(ctxb, Wot, bo, 1.0f, op, nullptr, m0, n0);
}

// ---------------- MFMA banded attention: 64 q-rows/block, 4 waves x 16 rows ----------------
// Zero-fill issued FIRST (drains under both passes); K direct from global (L2-resident);
// V double-buffered in LDS (transpose needed).
__global__ __launch_bounds__(256, 4) void attn_mfma(
    const ushort* __restrict__ qb, const ushort* __restrict__ kb, const ushort* __restrict__ vb,
    float* __restrict__ attn, ushort* __restrict__ ctxb)
{
    __shared__ alignas(16) ushort Vt[2][64 * 72];
    __shared__ alignas(16) ushort Pl[4][16 * 72];

    const int qblk = blockIdx.x, h = blockIdx.y, b = blockIdx.z;
    const int i0 = qblk * 64;
    const int t = threadIdx.x;
    const int w = t >> 6, l = t & 63;
    const int g = l >> 4, c = l & 15;
    const int ibase = i0 + w * 16;

    const int jstart = max(0, i0 - 256);            // 64-aligned
    const int jend = min(SS, i0 + 64 + 256);        // 64-aligned

    // Q A-fragments (rows ibase..ibase+15, pre-scaled via Wq)
    const size_t qoff = (size_t)(b * SS + ibase + c) * 1024 + h * 64 + g * 8;
    short8 aq0 = *(const short8*)&qb[qoff];
    short8 aq1 = *(const short8*)&qb[qoff + 32];

    // ---- zero-fill attn outside [jstart, jend) FIRST: stores drain under all later compute ----
    {
        float* ab = attn + (size_t)(b * HH + h) * SS * SS;
        const floatx4 z4 = {0.f, 0.f, 0.f, 0.f};
        const int g16 = t >> 4, c16 = t & 15;
#pragma unroll
        for (int rr = 0; rr < 4; ++rr) {
            float* rp = ab + (size_t)(i0 + g16 + rr * 16) * SS;
            for (int x = c16 * 4; x < jstart; x += 64)
                __builtin_nontemporal_store(z4, (floatx4*)&rp[x]);
            for (int x = jend + c16 * 4; x < SS; x += 64)
                __builtin_nontemporal_store(z4, (floatx4*)&rp[x]);
        }
    }

    const int vj0 = (t & 31) * 2, vd0 = (t >> 5) * 8;
    const ushort* Kbh = &kb[(size_t)(b * SS) * 1024 + h * 64];

    float m[4] = {-3e38f, -3e38f, -3e38f, -3e38f};
    float ll[4] = {0.f, 0.f, 0.f, 0.f};

    // ---- pass 1: running row max + sum (exp2 domain); K direct from global, no barriers ----
    for (int jt = jstart; jt < jend; jt += 64) {
        const ushort* kt = Kbh + (size_t)jt * 1024;
        floatx4 s[4] = {};
#pragma unroll
        for (int u = 0; u < 4; ++u) {
            short8 b0 = *(const short8*)&kt[(size_t)(u * 16 + c) * 1024 + g * 8];
            short8 b1 = *(const short8*)&kt[(size_t)(u * 16 + c) * 1024 + 32 + g * 8];
            s[u] = __builtin_amdgcn_mfma_f32_16x16x32_bf16(aq0, b0, s[u], 0, 0, 0);
            s[u] = __builtin_amdgcn_mfma_f32_16x16x32_bf16(aq1, b1, s[u], 0, 0, 0);
        }
        const bool full = (jt >= ibase - 240) && (jt <= ibase + 192);
#pragma unroll
        for (int r = 0; r < 4; ++r) {
            float v0 = s[0][r] * LOG2E, v1 = s[1][r] * LOG2E,
                  v2 = s[2][r] * LOG2E, v3 = s[3][r] * LOG2E;
            if (!full) {
                const int i = ibase + g * 4 + r;
                const int j0 = jt + c;
                if ((unsigned)(i - j0 + 255) >= 511u)        v0 = -3e38f;
                if ((unsigned)(i - (j0 + 16) + 255) >= 511u) v1 = -3e38f;
                if ((unsigned)(i - (j0 + 32) + 255) >= 511u) v2 = -3e38f;
                if ((unsigned)(i - (j0 + 48) + 255) >= 511u) v3 = -3e38f;
            }
            float tmax = fmaxf(fmaxf(v0, v1), fmaxf(v2, v3));
            float mn = fmaxf(m[r], tmax);
            float sc_ = EXP2F(m[r] - mn);
            float add = EXP2F(v0 - mn) + EXP2F(v1 - mn)
                      + EXP2F(v2 - mn) + EXP2F(v3 - mn);
            ll[r] = ll[r] * sc_ + add;
            m[r] = mn;
        }
    }

    // ---- finalize softmax stats across the 16 j-lanes of each row ----
    float M[4], invL[4];
#pragma unroll
    for (int r = 0; r < 4; ++r) {
        float mm = m[r];
        mm = fmaxf(mm, __shfl_xor(mm, 1));
        mm = fmaxf(mm, __shfl_xor(mm, 2));
        mm = fmaxf(mm, __shfl_xor(mm, 4));
        mm = fmaxf(mm, __shfl_xor(mm, 8));
        float la = ll[r] * EXP2F(m[r] - mm);
        la += __shfl_xor(la, 1);
        la += __shfl_xor(la, 2);
        la += __shfl_xor(la, 4);
        la += __shfl_xor(la, 8);
        M[r] = mm;
        invL[r] = 1.0f / la;
    }

    // ---- pass 2 prologue: stage V tile jstart into Vt[0] ----
    {
        const ushort* vr = &vb[(size_t)(b * SS + jstart + vj0) * 1024 + h * 64 + vd0];
        short8 v0 = *(const short8*)vr;
        short8 v1 = *(const short8*)(vr + 1024);
#pragma unroll
        for (int e = 0; e < 8; ++e) {
            ushort2 pr; pr.x = (ushort)v0[e]; pr.y = (ushort)v1[e];
            *(ushort2*)&Vt[0][(vd0 + e) * 72 + vj0] = pr;
        }
    }
    __syncthreads();

    // ---- pass 2: probs -> attn + PV; one barrier per tile ----
    floatx4 ctx[4] = {};
    int cur = 0;
    for (int jt = jstart; jt < jend; jt += 64) {
        const bool have = (jt + 64 < jend);
        short8 nv0, nv1;
        if (have) {  // T14: issue next V loads early
            const ushort* vr = &vb[(size_t)(b * SS + jt + 64 + vj0) * 1024 + h * 64 + vd0];
            nv0 = *(const short8*)vr;
            nv1 = *(const short8*)(vr + 1024);
        }
        // QK^T from global K
        const ushort* kt = Kbh + (size_t)jt * 1024;
        floatx4 s[4] = {};
#pragma unroll
        for (int u = 0; u < 4; ++u) {
            short8 b0 = *(const short8*)&kt[(size_t)(u * 16 + c) * 1024 + g * 8];
            short8 b1 = *(const short8*)&kt[(size_t)(u * 16 + c) * 1024 + 32 + g * 8];
            s[u] = __builtin_amdgcn_mfma_f32_16x16x32_bf16(aq0, b0, s[u], 0, 0, 0);
            s[u] = __builtin_amdgcn_mfma_f32_16x16x32_bf16(aq1, b1, s[u], 0, 0, 0);
        }
        const bool full = (jt >= ibase - 240) && (jt <= ibase + 192);
#pragma unroll
        for (int u = 0; u < 4; ++u) {
#pragma unroll
            for (int r = 0; r < 4; ++r) {
                float v = s[u][r] * LOG2E;
                if (!full) {
                    const int i = ibase + g * 4 + r;
                    const int j = jt + u * 16 + c;
                    if ((unsigned)(i - j + 255) >= 511u) v = -3e38f;
                }
                float p = EXP2F(v - M[r]) * invL[r];
                Pl[w][(g * 4 + r) * 72 + u * 16 + c] = f2b(p);
            }
        }
        // write attn band tile (256B contiguous per row-quarter), nontemporal
#pragma unroll
        for (int it = 0; it < 4; ++it) {
            const int row = it * 4 + g;
            ushort4 pw = *(const ushort4*)&Pl[w][row * 72 + c * 4];
            floatx4 o;
            o[0] = b2f(pw.x); o[1] = b2f(pw.y); o[2] = b2f(pw.z); o[3] = b2f(pw.w);
            __builtin_nontemporal_store(o,
                (floatx4*)&attn[(size_t)(b * HH + h) * SS * SS + (size_t)(ibase + row) * SS + jt + c * 4]);
        }
        // PV: ctx += P @ V  (Vt[cur] staged last iteration)
#pragma unroll
        for (int jc = 0; jc < 2; ++jc) {
            short8 pa = *(const short8*)&Pl[w][c * 72 + jc * 32 + g * 8];
#pragma unroll
            for (int ds = 0; ds < 4; ++ds) {
                short8 bv_ = *(const short8*)&Vt[cur][(ds * 16 + c) * 72 + jc * 32 + g * 8];
                ctx[ds] = __builtin_amdgcn_mfma_f32_16x16x32_bf16(pa, bv_, ctx[ds], 0, 0, 0);
            }
        }
        // T14 write-late: commit next V tile to LDS
        if (have) {
#pragma unroll
            for (int e = 0; e < 8; ++e) {
                ushort2 pr; pr.x = (ushort)nv0[e]; pr.y = (ushort)nv1[e];
                *(ushort2*)&Vt[cur ^ 1][(vd0 + e) * 72 + vj0] = pr;
            }
        }
        __syncthreads();
        cur ^= 1;
    }

    // ---- ctx out (bf16) ----
#pragma unroll
    for (int ds = 0; ds < 4; ++ds)
#pragma unroll
        for (int r = 0; r < 4; ++r)
            ctxb[(size_t)(b * SS + ibase + g * 4 + r) * 1024 + h * 64 + ds * 16 + c] = f2b(ctx[ds][r]);
}

// ---------------- residual + LayerNorm ----------------
__global__ __launch_bounds__(256) void ln_kernel(
    const float* __restrict__ op, const float* __restrict__ Qin,
    const float* __restrict__ gamma, const float* __restrict__ beta,
    float* __restrict__ y)
{
    const int row = blockIdx.x;
    const int t = threadIdx.x;
    __shared__ float rs[4], rss[4];

    float4 o4 = *(const float4*)&op[(size_t)row * 1024 + t * 4];
    float4 q4 = *(const float4*)&Qin[(size_t)row * 1024 + t * 4];
    float x0 = o4.x + q4.x, x1 = o4.y + q4.y, x2 = o4.z + q4.z, x3 = o4.w + q4.w;
    float s = x0 + x1 + x2 + x3;
    float ss = x0 * x0 + x1 * x1 + x2 * x2 + x3 * x3;
#pragma unroll
    for (int off = 1; off < 64; off <<= 1) {
        s  += __shfl_xor(s, off, 64);
        ss += __shfl_xor(ss, off, 64);
    }
    int wid = t >> 6;
    if ((t & 63) == 0) { rs[wid] = s; rss[wid] = ss; }
    __syncthreads();
    s  = rs[0] + rs[1] + rs[2] + rs[3];
    ss = rss[0] + rss[1] + rss[2] + rss[3];
    float mu = s * (1.0f / 1024.0f);
    float var = ss * (1.0f / 1024.0f) - mu * mu;
    float rstd = rsqrtf(var + LN_EPS);
    float4 g4 = *(const float4*)&gamma[t * 4];
    float4 b4 = *(const float4*)&beta[t * 4];
    float4 o;
    o.x = (x0 - mu) * rstd * g4.x + b4.x;
    o.y = (x1 - mu) * rstd * g4.y + b4.y;
    o.z = (x2 - mu) * rstd * g4.z + b4.z;
    o.w = (x3 - mu) * rstd * g4.w + b4.w;
    *(float4*)&y[(size_t)row * 1024 + t * 4] = o;
}

extern "C" void kernel_launch(void* const* d_in, const int* in_sizes, int n_in,
                              void* d_out, int out_size, void* d_ws, size_t ws_size,
                              hipStream_t stream) {
    (void)in_sizes; (void)n_in; (void)out_size; (void)ws_size;
    const float* Q  = (const float*)d_in[0];
    const float* K  = (const float*)d_in[1];
    const float* V  = (const float*)d_in[2];
    const float* Wq = (const float*)d_in[3];
    const float* bq = (const float*)d_in[4];
    const float* Wk = (const float*)d_in[5];
    const float* bk = (const float*)d_in[6];
    const float* Wv = (const float*)d_in[7];
    const float* bv = (const float*)d_in[8];
    const float* Wo = (const float*)d_in[9];
    const float* bo = (const float*)d_in[10];
    const float* gamma = (const float*)d_in[11];
    const float* beta  = (const float*)d_in[12];

    float* y = (float*)d_out;
    float* attn = y + (size_t)BB * SS * 1024;

    // workspace layout (bytes):
    //  [0,16M):  op (fp32)            -- aliased early by Xq (0-8M) + Xk (8-16M)
    //  [16M,24M): ctxb (bf16)         -- aliased early by Xv
    //  [24M,48M): qbp/kbp/vbp (bf16)
    //  [48M,56M): Wqt/Wkt/Wvt/Wot (bf16)
    char* base = (char*)d_ws;
    float*  op   = (float*)base;
    ushort* Xq   = (ushort*)base;                         // dead after gemm_qkv
    ushort* Xk   = (ushort*)(base + (size_t)8 * 1048576);
    ushort* Xv   = (ushort*)(base + (size_t)16 * 1048576);
    ushort* ctxb = (ushort*)(base + (size_t)16 * 1048576);
    ushort* qbp  = (ushort*)(base + (size_t)24 * 1048576);
    ushort* kbp  = (ushort*)(base + (size_t)32 * 1048576);
    ushort* vbp  = (ushort*)(base + (size_t)40 * 1048576);
    ushort* Wqt  = (ushort*)(base + (size_t)48 * 1048576);
    ushort* Wkt  = (ushort*)(base + (size_t)50 * 1048576);
    ushort* Wvt  = (ushort*)(base + (size_t)52 * 1048576);
    ushort* Wot  = (ushort*)(base + (size_t)54 * 1048576);

    prep<<<dim3(2048, 1, 7), 256, 0, stream>>>(Q, K, V, Wq, Wk, Wv, Wo,
                                               Xq, Xk, Xv, Wqt, Wkt, Wvt, Wot);
    gemm_qkv<<<dim3(8, 32, 3), 256, 0, stream>>>(Xq, Xk, Xv, Wqt, Wkt, Wvt, bq, bk, bv, qbp, kbp, vbp);
    attn_mfma<<<dim3(SS / 64, HH, BB), 256, 0, stream>>>(qbp, kbp, vbp, attn, ctxb);
    gemm_obf<<<dim3(8, 64), 256, 0, stream>>>(ctxb, Wot, bo, op);
    ln_kernel<<<4096, 256, 0, stream>>>(op, Q, gamma, beta, y);
}